// Round 1
// 60.934 us; speedup vs baseline: 1.0098x; 1.0098x over previous
//
#include <hip/hip_runtime.h>
#include <math.h>

// DendriticLayer, time-parallel formulation.
// N_IN=1024, N_OUT=256, B=512, T=100, dt=1, tau_syn=5, tau_mem=10, tau_soft=0.5
// CONN: output o reads exactly inputs [4o, 4o+4).
//
// Algebra: psp_j(t) = [t>=s_j] w_j e^{-(t-s_j)/5} = [t>=s_j] A_j u^t,
//          A_j = w_j e^{s_j/5}, u = e^{-1/5}.
// v_t = 0.9 v_{t-1} + 0.1 u^t S_t,   S_t = sum_j [t>=s_j] A_j  (piecewise const).
// LINEAR in the input => the 100-step scan splits into 4 chunks of 25:
//   zero-state chunk end value (exact geometric sum, since S_t changes only at
//   c_j = ceil(s_j)):   zend = C1 * sum_j A'_j (r^{n_j} - 1),
//     r = 0.9/u, C1 = u^24/(r-1), n_j = clamp(25 - ceil(s_j - t0), 0, 25)
//   boundary combine:   v_end(c) = zend(c) + 0.9^25 v_end(c-1)   (Horner, LDS)
// Everything is carried pre-scaled by K = 2*log2(e) so the softmax weight
// exp(v/tau_soft) is a single v_exp_f32 (exp2) on the carried state.
//
// Why: previous kernel ran 2048 waves (2/SIMD, grid-limited) with a serial
// 100-step chain (fma -> exp -> accum) => latency-bound at ~13% of the issue
// ceiling (~21 us vs ~2.7 us floor). This version: 8192 waves (8/SIMD target),
// 4x shorter chains, same per-step cost.

#define N_IN   1024
#define N_OUT  256
#define BATCH  512
#define NCHUNK 4
#define CLEN   25
#define OTILE  128
#define TPB    (NCHUNK * OTILE)   // 512 threads = 8 waves

#if __has_builtin(__builtin_amdgcn_exp2f)
#define EXP2(x) __builtin_amdgcn_exp2f(x)        // raw v_exp_f32
#else
#define EXP2(x) __expf(0.69314718056f * (x))     // same units fallback
#endif

// launch_bounds(512, 8): 8 waves/EU min -> 4 blocks/CU -> VGPR cap 64.
// ~30 live VGPRs expected; if -Rpass-analysis ever shows spills, drop to (TPB, 4).
__global__ __launch_bounds__(TPB, 8) void dendritic_kernel(
    const float* __restrict__ spikes,  // [B, N_IN]
    const float* __restrict__ W,       // [N_OUT, N_IN]
    float* __restrict__ out)           // [B, N_OUT]
{
    const int b     = blockIdx.x >> 1;
    const int obase = (blockIdx.x & 1) * OTILE;
    const int tid   = threadIdx.x;
    const int ol    = tid & (OTILE - 1);
    const int c     = tid >> 7;             // chunk 0..3, wave-uniform
    const int o     = obase + ol;
    const float t0f = (float)(CLEN * c);

    // Coalesced float4 loads (3 MB total input, L2/L3-resident; 4x re-read is free)
    const float4 s4 = *reinterpret_cast<const float4*>(spikes + b * N_IN + o * 4);
    const float4 w4 = *reinterpret_cast<const float4*>(W + o * N_IN + o * 4);

    // ---- compile-time constants (all const-folded literals) ----
    const float KB    = 2.0f * 1.44269504089f * 0.1f;            // K*beta
    const float L2E5  = 0.2f * 1.44269504089f;                   // log2(e)/tau_syn
    const float LOG2R = L2E5 + __builtin_log2f(0.9f);            // log2(0.9 e^{0.2})
    const float C1    = __builtin_expf(-4.8f) /
                        (0.9f * __builtin_expf(0.2f) - 1.0f);    // u^24/(r-1)
    const float G1    = __builtin_expf(25.0f * __builtin_logf(0.9f)); // 0.9^25

    // U0 = K*beta*u^{t0}: chunk literal, folded into the amplitudes once.
    const float U0 = (c == 0) ? KB
                   : (c == 1) ? KB * __builtin_expf(-5.0f)
                   : (c == 2) ? KB * __builtin_expf(-10.0f)
                   :            KB * __builtin_expf(-15.0f);

    // Scaled amplitudes A'_j = K*beta*u^{t0} * w_j * e^{s_j/5}
    const float a0 = (w4.x * U0) * EXP2(L2E5 * s4.x);
    const float a1 = (w4.y * U0) * EXP2(L2E5 * s4.y);
    const float a2 = (w4.z * U0) * EXP2(L2E5 * s4.z);
    const float a3 = (w4.w * U0) * EXP2(L2E5 * s4.w);

    // Chunk-local spike times; boundary-relevant cases are exact in fp32
    const float sh0 = s4.x - t0f, sh1 = s4.y - t0f,
                sh2 = s4.z - t0f, sh3 = s4.w - t0f;

    // ---- phase 1: closed-form zero-state chunk end value ----
    const float n0 = fminf(25.0f, fmaxf(0.0f, 25.0f - __builtin_ceilf(sh0)));
    const float n1 = fminf(25.0f, fmaxf(0.0f, 25.0f - __builtin_ceilf(sh1)));
    const float n2 = fminf(25.0f, fmaxf(0.0f, 25.0f - __builtin_ceilf(sh2)));
    const float n3 = fminf(25.0f, fmaxf(0.0f, 25.0f - __builtin_ceilf(sh3)));
    const float zend = C1 * (a0 * (EXP2(LOG2R * n0) - 1.0f) +
                             a1 * (EXP2(LOG2R * n1) - 1.0f) +
                             a2 * (EXP2(LOG2R * n2) - 1.0f) +
                             a3 * (EXP2(LOG2R * n3) - 1.0f));

    __shared__ float zl[NCHUNK][OTILE];    // stride-1 across lanes: conflict-free
    zl[c][ol] = zend;
    __syncthreads();

    // ---- boundary combine: v_start = sum_{k<c} g^{c-1-k} zend(k)  (Horner) ----
    float v = 0.0f;                         // wave-uniform branches
    if (c == 1)      v = zl[0][ol];
    else if (c == 2) v = fmaf(G1, zl[0][ol], zl[1][ol]);
    else if (c == 3) v = fmaf(G1, fmaf(G1, zl[0][ol], zl[1][ol]), zl[2][ol]);

    // ---- phase 2: 25 true steps, exp + accumulate ----
    // per step: 4 cmp + 4 cndmask + 3 add + mul + fma + exp2 + add + fma = 15
    float den0 = 0.f, den1 = 0.f, den2 = 0.f, den3 = 0.f;
    float num0 = 0.f, num1 = 0.f, num2 = 0.f, num3 = 0.f;
#pragma unroll
    for (int k = 0; k < CLEN; ++k) {
        const float kf = (float)k;                       // literal
        const float uk = __builtin_expf(-0.2f * kf);     // const-folded literal
        float S = (sh0 <= kf ? a0 : 0.f) + (sh1 <= kf ? a1 : 0.f)
                + (sh2 <= kf ? a2 : 0.f) + (sh3 <= kf ? a3 : 0.f);
        v = fmaf(0.9f, v, uk * S);                       // scaled recurrence
        const float e = EXP2(v);                         // softmax weight 2^{Kv}
        if      ((k & 3) == 0) { den0 += e; num0 = fmaf(e, kf, num0); }
        else if ((k & 3) == 1) { den1 += e; num1 = fmaf(e, kf, num1); }
        else if ((k & 3) == 2) { den2 += e; num2 = fmaf(e, kf, num2); }
        else                   { den3 += e; num3 = fmaf(e, kf, num3); }
    }

    const float den = (den0 + den1) + (den2 + den3);
    // local times were k = t - t0  =>  num += t0 * den
    const float num = fmaf(t0f, den, (num0 + num1) + (num2 + num3));

    // ---- cross-chunk softmax reduce ----
    __shared__ float2 red[NCHUNK][OTILE];  // 8B/lane: 2-way alias, free
    red[c][ol] = make_float2(num, den);
    __syncthreads();

    if (c == 0) {
        const float2 r0 = red[0][ol], r1 = red[1][ol],
                     r2 = red[2][ol], r3 = red[3][ol];
        out[b * N_OUT + o] = ((r0.x + r1.x) + (r2.x + r3.x)) /
                             ((r0.y + r1.y) + (r2.y + r3.y));
    }
}

extern "C" void kernel_launch(void* const* d_in, const int* in_sizes, int n_in,
                              void* d_out, int out_size, void* d_ws, size_t ws_size,
                              hipStream_t stream) {
    const float* spikes = (const float*)d_in[0];  // [512, 1024]
    const float* W      = (const float*)d_in[1];  // [256, 1024]
    float* out          = (float*)d_out;          // [512, 256]

    dendritic_kernel<<<BATCH * 2, TPB, 0, stream>>>(spikes, W, out);
}